// Round 2
// baseline (1314.571 us; speedup 1.0000x reference)
//
#include <hip/hip_runtime.h>
#include <hip/hip_bf16.h>

typedef __attribute__((ext_vector_type(4))) float f32x4;
typedef __attribute__((ext_vector_type(8))) short short8;
typedef __attribute__((ext_vector_type(4))) short short4_t;

#define NWIN 4096
#define LTOK 64
#define CDIM 256

static __device__ __forceinline__ short f2bf(float f) {
    __hip_bfloat16 h = __float2bfloat16(f);
    union { __hip_bfloat16 b; short s; } u; u.b = h;
    return u.s;
}

// ---------------- prep kernels ----------------
// Weights pre-swizzled into MFMA B-fragment order so the main kernel's
// fragment load is one fully-coalesced 1KB wave load:
//   wqs[((ntile*8 + kt)*64 + lane)*8 + j] = wq[ntile*16 + (lane%16)][kt*32 + (lane/16)*8 + j]
__global__ void prep_weights(const float* __restrict__ qw, const float* __restrict__ pw,
                             short* __restrict__ wqs, short* __restrict__ wps) {
    int i = blockIdx.x * 256 + threadIdx.x;     // grid 768*256 = 196608
    if (i < 768 * 256) {
        int row = i >> 8, col = i & 255;
        int nt = row >> 4, lcr = row & 15;
        int kt = col >> 5, lg = (col >> 3) & 3, j = col & 7;
        wqs[(size_t)(((nt * 8 + kt) * 64) + lg * 16 + lcr) * 8 + j] = f2bf(qw[i]);
    }
    if (i < 256 * 256) {
        int row = i >> 8, col = i & 255;
        int ww = row >> 6, ntl = (row >> 4) & 3, lcr = row & 15;
        int h = col >> 5, lg = (col >> 3) & 3, j = col & 7;
        wps[(size_t)((((ww * 4 + ntl) * 8 + h) * 64) + lg * 16 + lcr) * 8 + j] = f2bf(pw[i]);
    }
}

__global__ void prep_bias(const float* __restrict__ w1, const float* __restrict__ b1,
                          const float* __restrict__ w2, const float* __restrict__ b2,
                          const float* __restrict__ lsc, float* __restrict__ biasT,
                          float* __restrict__ scT) {
    int t = threadIdx.x;                         // 1 block, 128 threads
    if (t < 8) scT[t] = expf(fminf(lsc[t], logf(100.0f)));
    if (t < 127) {
        float delta = (float)(t - 63);
        float sg = (delta > 0.f) ? 1.f : ((delta < 0.f) ? -1.f : 0.f);
        float r = sg * log1pf(fabsf(delta));
        float acc[8];
        #pragma unroll
        for (int q = 0; q < 8; ++q) acc[q] = b2[q];
        for (int m = 0; m < 384; ++m) {
            float hid = fmaxf(fmaf(r, w1[m * 2 + 1], b1[m]), 0.f);
            #pragma unroll
            for (int q = 0; q < 8; ++q) acc[q] = fmaf(hid, w2[q * 384 + m], acc[q]);
        }
        #pragma unroll
        for (int q = 0; q < 8; ++q) biasT[q * 127 + t] = acc[q];
    }
}

// ---------------- main fused kernel ----------------
// one block per window; 4 waves; X tile held in registers (128 VGPR bf16);
// head-pair loop with 3 barriers per pair; proj accumulated across heads.

__global__ void __launch_bounds__(256, 2)
fused_win_attn(const float* __restrict__ x,
               const float* __restrict__ qkv_b,
               const float* __restrict__ proj_b,
               const short* __restrict__ wqs,
               const short* __restrict__ wps,
               const float* __restrict__ biasT,
               const float* __restrict__ scT,
               float* __restrict__ out)
{
    __shared__ short QG[64 * 72];          // q pair, [token][d0..63], stride 72
    __shared__ short KG[64 * 72];          // k pair
    __shared__ short VT[64 * 72];          // v pair transposed: [d][token]
    __shared__ short PBs[2][64 * 72];      // softmaxed P per head
    __shared__ short AOs[2][64 * 40];      // attn out per head, [token][d0..31], stride 40
    __shared__ float NSQ[2 * 64 * 4];      // sumsq partials [qk][row][strip]
    __shared__ float BT[8 * 128];          // bias table [h][rel+63]

    const int tid = threadIdx.x;
    const int w  = tid >> 6;
    const int l  = tid & 63;
    const int lg = l >> 4;
    const int lc = l & 15;
    const int blk = blockIdx.x;

    // ---- stage bias table into LDS (completes before first use after B1) ----
    #pragma unroll
    for (int u = 0; u < 4; ++u) {
        int idx = u * 256 + tid;
        if (idx < 8 * 127) {
            int h = idx / 127, d = idx - h * 127;
            BT[h * 128 + d] = biasT[idx];
        }
    }

    // ---- load X tile into registers as bf16 MFMA A-fragments ----
    // xf[mt][kt]: lane (lg,lc) holds x[mt*16+lc][kt*32 + lg*8 .. +7]
    short8 xf[4][8];
    {
        const float* xb = x + (size_t)blk * (LTOK * CDIM) + (size_t)lc * CDIM + lg * 8;
        #pragma unroll
        for (int mt = 0; mt < 4; ++mt) {
            #pragma unroll
            for (int kt = 0; kt < 8; ++kt) {
                f32x4 a = *(const f32x4*)(xb + mt * 16 * CDIM + kt * 32);
                f32x4 b = *(const f32x4*)(xb + mt * 16 * CDIM + kt * 32 + 4);
                short8 t;
                t[0] = f2bf(a[0]); t[1] = f2bf(a[1]); t[2] = f2bf(a[2]); t[3] = f2bf(a[3]);
                t[4] = f2bf(b[0]); t[5] = f2bf(b[1]); t[6] = f2bf(b[2]); t[7] = f2bf(b[3]);
                xf[mt][kt] = t;
            }
        }
    }

    f32x4 accP[4][4];      // proj accumulators: [mt][ntl], persist across heads
    #pragma unroll
    for (int a = 0; a < 4; ++a)
        #pragma unroll
        for (int bb = 0; bb < 4; ++bb)
            accP[a][bb] = (f32x4){0.f, 0.f, 0.f, 0.f};

    const f32x4 fzero = {0.f, 0.f, 0.f, 0.f};

    #pragma unroll 1
    for (int g = 0; g < 4; ++g) {
        // ---- qkv GEMM for heads 2g, 2g+1: wave w does a 16-col strip of q,k,v ----
        #pragma unroll
        for (int s = 0; s < 3; ++s) {
            const int cbt = s * 16 + g * 4 + w;               // output n-tile index
            const float bq = qkv_b[s * 256 + g * 64 + w * 16 + lc];
            f32x4 acc[4];
            acc[0] = acc[1] = acc[2] = acc[3] = fzero;
            #pragma unroll
            for (int kt = 0; kt < 8; ++kt) {
                short8 Bf = *(const short8*)(wqs + (size_t)((cbt * 8 + kt) * 64 + l) * 8);
                #pragma unroll
                for (int mt = 0; mt < 4; ++mt)
                    acc[mt] = __builtin_amdgcn_mfma_f32_16x16x32_bf16(xf[mt][kt], Bf, acc[mt], 0, 0, 0);
            }
            if (s < 2) {
                short* dst = (s == 0) ? QG : KG;
                #pragma unroll
                for (int mt = 0; mt < 4; ++mt) {
                    #pragma unroll
                    for (int i = 0; i < 4; ++i) {
                        float v = acc[mt][i] + bq;
                        dst[(mt * 16 + lg * 4 + i) * 72 + (w * 16 + lc)] = f2bf(v);
                        float t = v * v;
                        t += __shfl_xor(t, 1);
                        t += __shfl_xor(t, 2);
                        t += __shfl_xor(t, 4);
                        t += __shfl_xor(t, 8);
                        if (lc == 0) NSQ[s * 256 + (mt * 16 + lg * 4 + i) * 4 + w] = t;
                    }
                }
            } else {
                // v: transpose-store VT[d_local][token]
                #pragma unroll
                for (int mt = 0; mt < 4; ++mt) {
                    short4_t pk;
                    #pragma unroll
                    for (int i = 0; i < 4; ++i) pk[i] = f2bf(acc[mt][i] + bq);
                    *(short4_t*)(VT + (w * 16 + lc) * 72 + mt * 16 + lg * 4) = pk;
                }
            }
        }
        __syncthreads();                                       // B1

        // ---- QK^T + softmax, both heads ----
        #pragma unroll
        for (int hh = 0; hh < 2; ++hh) {
            const int h = 2 * g + hh;
            const float sc = scT[h];
            short8 Aq = *(const short8*)(QG + (w * 16 + lc) * 72 + hh * 32 + lg * 8);
            f32x4 pacc[4];
            #pragma unroll
            for (int nt = 0; nt < 4; ++nt) {
                short8 Bk = *(const short8*)(KG + (nt * 16 + lc) * 72 + hh * 32 + lg * 8);
                pacc[nt] = __builtin_amdgcn_mfma_f32_16x16x32_bf16(Aq, Bk, fzero, 0, 0, 0);
            }
            float invq[4], invk[4];
            #pragma unroll
            for (int i = 0; i < 4; ++i) {
                int r = w * 16 + lg * 4 + i;
                invq[i] = rsqrtf(NSQ[r * 4 + 2 * hh] + NSQ[r * 4 + 2 * hh + 1] + 1e-24f) * sc;
            }
            #pragma unroll
            for (int nt = 0; nt < 4; ++nt) {
                int rk = nt * 16 + lc;
                invk[nt] = rsqrtf(NSQ[256 + rk * 4 + 2 * hh] + NSQ[256 + rk * 4 + 2 * hh + 1] + 1e-24f);
            }
            float p[4][4];
            #pragma unroll
            for (int i = 0; i < 4; ++i) {
                int r = w * 16 + lg * 4 + i;
                #pragma unroll
                for (int nt = 0; nt < 4; ++nt) {
                    int c = nt * 16 + lc;
                    p[i][nt] = pacc[nt][i] * invq[i] * invk[nt] + BT[h * 128 + r - c + 63];
                }
            }
            #pragma unroll
            for (int i = 0; i < 4; ++i) {
                float m = fmaxf(fmaxf(p[i][0], p[i][1]), fmaxf(p[i][2], p[i][3]));
                m = fmaxf(m, __shfl_xor(m, 1));
                m = fmaxf(m, __shfl_xor(m, 2));
                m = fmaxf(m, __shfl_xor(m, 4));
                m = fmaxf(m, __shfl_xor(m, 8));
                float ssum = 0.f;
                #pragma unroll
                for (int nt = 0; nt < 4; ++nt) { p[i][nt] = __expf(p[i][nt] - m); ssum += p[i][nt]; }
                ssum += __shfl_xor(ssum, 1);
                ssum += __shfl_xor(ssum, 2);
                ssum += __shfl_xor(ssum, 4);
                ssum += __shfl_xor(ssum, 8);
                float rinv = 1.f / ssum;
                #pragma unroll
                for (int nt = 0; nt < 4; ++nt)
                    PBs[hh][(w * 16 + lg * 4 + i) * 72 + nt * 16 + lc] = f2bf(p[i][nt] * rinv);
            }
        }
        __syncthreads();                                       // B2

        // ---- P @ V, both heads ----
        #pragma unroll
        for (int hh = 0; hh < 2; ++hh) {
            f32x4 oacc[2];
            oacc[0] = oacc[1] = fzero;
            #pragma unroll
            for (int kt = 0; kt < 2; ++kt) {
                short8 Ap = *(const short8*)(PBs[hh] + (w * 16 + lc) * 72 + kt * 32 + lg * 8);
                #pragma unroll
                for (int nt2 = 0; nt2 < 2; ++nt2) {
                    short8 Bv = *(const short8*)(VT + (hh * 32 + nt2 * 16 + lc) * 72 + kt * 32 + lg * 8);
                    oacc[nt2] = __builtin_amdgcn_mfma_f32_16x16x32_bf16(Ap, Bv, oacc[nt2], 0, 0, 0);
                }
            }
            #pragma unroll
            for (int nt2 = 0; nt2 < 2; ++nt2)
                #pragma unroll
                for (int i = 0; i < 4; ++i)
                    AOs[hh][(w * 16 + lg * 4 + i) * 40 + nt2 * 16 + lc] = f2bf(oacc[nt2][i]);
        }
        __syncthreads();                                       // B3

        // ---- proj accumulate, both heads (overlaps with next g's qkv region) ----
        #pragma unroll
        for (int hh = 0; hh < 2; ++hh) {
            const int h = 2 * g + hh;
            #pragma unroll
            for (int mt = 0; mt < 4; ++mt) {
                short8 Aa = *(const short8*)(AOs[hh] + (mt * 16 + lc) * 40 + lg * 8);
                #pragma unroll
                for (int ntl = 0; ntl < 4; ++ntl) {
                    short8 Bp = *(const short8*)(wps + (size_t)(((w * 4 + ntl) * 8 + h) * 64 + l) * 8);
                    accP[mt][ntl] = __builtin_amdgcn_mfma_f32_16x16x32_bf16(Aa, Bp, accP[mt][ntl], 0, 0, 0);
                }
            }
        }
    }

    // ---- epilogue: out = accP + proj_b ----
    {
        float* ob = out + (size_t)blk * (LTOK * CDIM);
        float pbv[4];
        #pragma unroll
        for (int ntl = 0; ntl < 4; ++ntl) pbv[ntl] = proj_b[w * 64 + ntl * 16 + lc];
        #pragma unroll
        for (int mt = 0; mt < 4; ++mt)
            #pragma unroll
            for (int ntl = 0; ntl < 4; ++ntl)
                #pragma unroll
                for (int i = 0; i < 4; ++i)
                    ob[(mt * 16 + lg * 4 + i) * 256 + w * 64 + ntl * 16 + lc] = accP[mt][ntl][i] + pbv[ntl];
    }
}

extern "C" void kernel_launch(void* const* d_in, const int* in_sizes, int n_in,
                              void* d_out, int out_size, void* d_ws, size_t ws_size,
                              hipStream_t stream) {
    const float* x     = (const float*)d_in[0];
    const float* qkvw  = (const float*)d_in[1];
    const float* qkvb  = (const float*)d_in[2];
    const float* projw = (const float*)d_in[3];
    const float* projb = (const float*)d_in[4];
    const float* lsc   = (const float*)d_in[5];
    const float* w1    = (const float*)d_in[6];
    const float* b1    = (const float*)d_in[7];
    const float* w2    = (const float*)d_in[8];
    const float* b2    = (const float*)d_in[9];
    float* out = (float*)d_out;

    // workspace layout
    short* wqs   = (short*)d_ws;                          // 393216 B
    short* wps   = (short*)((char*)d_ws + 393216);        // 131072 B
    float* biasT = (float*)((char*)d_ws + 524288);        // 4096 B
    float* scT   = (float*)((char*)d_ws + 528384);        // 32 B

    const int nwin = in_sizes[0] / (LTOK * CDIM);         // 4096

    prep_weights<<<768, 256, 0, stream>>>(qkvw, projw, wqs, wps);
    prep_bias<<<1, 128, 0, stream>>>(w1, b1, w2, b2, lsc, biasT, scT);
    fused_win_attn<<<nwin, 256, 0, stream>>>(x, qkvb, projb, wqs, wps, biasT, scT, out);
}

// Round 3
// 583.760 us; speedup vs baseline: 2.2519x; 2.2519x over previous
//
#include <hip/hip_runtime.h>
#include <hip/hip_bf16.h>

typedef __attribute__((ext_vector_type(4))) float f32x4;
typedef __attribute__((ext_vector_type(8))) short short8;
typedef __attribute__((ext_vector_type(4))) short short4_t;

#define NWIN 4096
#define LTOK 64
#define CDIM 256

static __device__ __forceinline__ short f2bf(float f) {
    __hip_bfloat16 h = __float2bfloat16(f);
    union { __hip_bfloat16 b; short s; } u; u.b = h;
    return u.s;
}

// ---------------- prep kernels ----------------
// Weights pre-swizzled into MFMA B-fragment order so the main kernel's
// fragment load is one fully-coalesced 1KB wave load.
__global__ void prep_weights(const float* __restrict__ qw, const float* __restrict__ pw,
                             short* __restrict__ wqs, short* __restrict__ wps) {
    int i = blockIdx.x * 256 + threadIdx.x;     // grid 768*256 = 196608
    if (i < 768 * 256) {
        int row = i >> 8, col = i & 255;
        int nt = row >> 4, lcr = row & 15;
        int kt = col >> 5, lg = (col >> 3) & 3, j = col & 7;
        wqs[(size_t)(((nt * 8 + kt) * 64) + lg * 16 + lcr) * 8 + j] = f2bf(qw[i]);
    }
    if (i < 256 * 256) {
        int row = i >> 8, col = i & 255;
        int ww = row >> 6, ntl = (row >> 4) & 3, lcr = row & 15;
        int h = col >> 5, lg = (col >> 3) & 3, j = col & 7;
        wps[(size_t)((((ww * 4 + ntl) * 8 + h) * 64) + lg * 16 + lcr) * 8 + j] = f2bf(pw[i]);
    }
}

__global__ void prep_bias(const float* __restrict__ w1, const float* __restrict__ b1,
                          const float* __restrict__ w2, const float* __restrict__ b2,
                          const float* __restrict__ lsc, float* __restrict__ biasT,
                          float* __restrict__ scT) {
    int t = threadIdx.x;                         // 1 block, 128 threads
    if (t < 8) scT[t] = expf(fminf(lsc[t], logf(100.0f)));
    if (t < 127) {
        float delta = (float)(t - 63);
        float sg = (delta > 0.f) ? 1.f : ((delta < 0.f) ? -1.f : 0.f);
        float r = sg * log1pf(fabsf(delta));
        float acc[8];
        #pragma unroll
        for (int q = 0; q < 8; ++q) acc[q] = b2[q];
        for (int m = 0; m < 384; ++m) {
            float hid = fmaxf(fmaf(r, w1[m * 2 + 1], b1[m]), 0.f);
            #pragma unroll
            for (int q = 0; q < 8; ++q) acc[q] = fmaf(hid, w2[q * 384 + m], acc[q]);
        }
        #pragma unroll
        for (int q = 0; q < 8; ++q) biasT[q * 127 + t] = acc[q];
    }
}

// ---------------- main fused kernel ----------------
// one block per window; 4 waves; X in LDS; head-pair qkv, per-head attention;
// proj accumulated across heads in persistent accumulators.
// LDS total = 77824 B -> 2 blocks/CU (8 waves/CU).

__global__ void __launch_bounds__(256, 2)
fused_win_attn(const float* __restrict__ x,
               const float* __restrict__ qkv_b,
               const float* __restrict__ proj_b,
               const short* __restrict__ wqs,
               const short* __restrict__ wps,
               const float* __restrict__ biasT,
               const float* __restrict__ scT,
               float* __restrict__ out)
{
    __shared__ short XS[64 * 264];         // x tile bf16, stride 264      33792 B
    __shared__ short QG[64 * 72];          // q pair [token][d0..63]        9216 B
    __shared__ short KG[64 * 72];          // k pair                        9216 B
    __shared__ short VT[64 * 72];          // v pair transposed [d][token]  9216 B
    __shared__ short PB[64 * 72];          // softmaxed P (one head)        9216 B
    __shared__ short AO[64 * 40];          // attn out (one head)           5120 B
    __shared__ float NSQ[2 * 64 * 4];      // sumsq partials                2048 B

    const int tid = threadIdx.x;
    const int w  = tid >> 6;
    const int l  = tid & 63;
    const int lg = l >> 4;
    const int lc = l & 15;
    const int blk = blockIdx.x;

    // ---- stage x -> XS: each thread converts 8 consecutive floats -> one short8 write ----
    // write addr: row*528B + (tid&31)*16B -> contiguous 512B per 32-lane group: conflict-free
    {
        const float* xb = x + (size_t)blk * (LTOK * CDIM);
        #pragma unroll
        for (int u = 0; u < 8; ++u) {
            int base = u * 2048 + tid * 8;
            f32x4 a = *(const f32x4*)(xb + base);
            f32x4 b = *(const f32x4*)(xb + base + 4);
            int r = base >> 8;
            int c = base & 255;
            short8 t;
            t[0] = f2bf(a[0]); t[1] = f2bf(a[1]); t[2] = f2bf(a[2]); t[3] = f2bf(a[3]);
            t[4] = f2bf(b[0]); t[5] = f2bf(b[1]); t[6] = f2bf(b[2]); t[7] = f2bf(b[3]);
            *(short8*)(XS + r * 264 + c) = t;
        }
    }

    f32x4 accP[4][4];      // proj accumulators: [mt][ntl], persist across heads
    #pragma unroll
    for (int a = 0; a < 4; ++a)
        #pragma unroll
        for (int bb = 0; bb < 4; ++bb)
            accP[a][bb] = (f32x4){0.f, 0.f, 0.f, 0.f};

    const f32x4 fzero = {0.f, 0.f, 0.f, 0.f};
    __syncthreads();                                           // XS ready

    #pragma unroll 1
    for (int g = 0; g < 4; ++g) {
        // ---- qkv GEMM for heads 2g,2g+1: wave w does a 16-col strip of q,k,v ----
        #pragma unroll
        for (int s = 0; s < 3; ++s) {
            const int cbt = s * 16 + g * 4 + w;               // output n-tile index
            const float bq = qkv_b[s * 256 + g * 64 + w * 16 + lc];
            f32x4 acc[4];
            acc[0] = acc[1] = acc[2] = acc[3] = fzero;
            #pragma unroll
            for (int kt = 0; kt < 8; ++kt) {
                short8 Bf = *(const short8*)(wqs + (size_t)((cbt * 8 + kt) * 64 + l) * 8);
                #pragma unroll
                for (int mt = 0; mt < 4; ++mt) {
                    short8 Af = *(const short8*)(XS + (mt * 16 + lc) * 264 + kt * 32 + lg * 8);
                    acc[mt] = __builtin_amdgcn_mfma_f32_16x16x32_bf16(Af, Bf, acc[mt], 0, 0, 0);
                }
            }
            if (s < 2) {
                short* dst = (s == 0) ? QG : KG;
                #pragma unroll
                for (int mt = 0; mt < 4; ++mt) {
                    #pragma unroll
                    for (int i = 0; i < 4; ++i) {
                        float v = acc[mt][i] + bq;
                        dst[(mt * 16 + lg * 4 + i) * 72 + (w * 16 + lc)] = f2bf(v);
                        float t = v * v;
                        t += __shfl_xor(t, 1);
                        t += __shfl_xor(t, 2);
                        t += __shfl_xor(t, 4);
                        t += __shfl_xor(t, 8);
                        if (lc == 0) NSQ[s * 256 + (mt * 16 + lg * 4 + i) * 4 + w] = t;
                    }
                }
            } else {
                // v: transpose-store VT[d_local][token]
                #pragma unroll
                for (int mt = 0; mt < 4; ++mt) {
                    short4_t pk;
                    #pragma unroll
                    for (int i = 0; i < 4; ++i) pk[i] = f2bf(acc[mt][i] + bq);
                    *(short4_t*)(VT + (w * 16 + lc) * 72 + mt * 16 + lg * 4) = pk;
                }
            }
        }
        __syncthreads();                                       // B1: qkv ready

        #pragma unroll 1
        for (int hh = 0; hh < 2; ++hh) {
            const int h = 2 * g + hh;
            const float sc = scT[h];
            // ---- QK^T: wave w = m-tile ----
            short8 Aq = *(const short8*)(QG + (w * 16 + lc) * 72 + hh * 32 + lg * 8);
            f32x4 pacc[4];
            #pragma unroll
            for (int nt = 0; nt < 4; ++nt) {
                short8 Bk = *(const short8*)(KG + (nt * 16 + lc) * 72 + hh * 32 + lg * 8);
                pacc[nt] = __builtin_amdgcn_mfma_f32_16x16x32_bf16(Aq, Bk, fzero, 0, 0, 0);
            }
            float invq[4], invk[4];
            #pragma unroll
            for (int i = 0; i < 4; ++i) {
                int r = w * 16 + lg * 4 + i;
                invq[i] = rsqrtf(NSQ[r * 4 + 2 * hh] + NSQ[r * 4 + 2 * hh + 1] + 1e-24f) * sc;
            }
            #pragma unroll
            for (int nt = 0; nt < 4; ++nt) {
                int rk = nt * 16 + lc;
                invk[nt] = rsqrtf(NSQ[256 + rk * 4 + 2 * hh] + NSQ[256 + rk * 4 + 2 * hh + 1] + 1e-24f);
            }
            float p[4][4];
            #pragma unroll
            for (int i = 0; i < 4; ++i) {
                int r = w * 16 + lg * 4 + i;
                #pragma unroll
                for (int nt = 0; nt < 4; ++nt) {
                    int c = nt * 16 + lc;
                    p[i][nt] = pacc[nt][i] * invq[i] * invk[nt] + biasT[h * 127 + r - c + 63];
                }
            }
            // ---- softmax ----
            #pragma unroll
            for (int i = 0; i < 4; ++i) {
                float m = fmaxf(fmaxf(p[i][0], p[i][1]), fmaxf(p[i][2], p[i][3]));
                m = fmaxf(m, __shfl_xor(m, 1));
                m = fmaxf(m, __shfl_xor(m, 2));
                m = fmaxf(m, __shfl_xor(m, 4));
                m = fmaxf(m, __shfl_xor(m, 8));
                float ssum = 0.f;
                #pragma unroll
                for (int nt = 0; nt < 4; ++nt) { p[i][nt] = __expf(p[i][nt] - m); ssum += p[i][nt]; }
                ssum += __shfl_xor(ssum, 1);
                ssum += __shfl_xor(ssum, 2);
                ssum += __shfl_xor(ssum, 4);
                ssum += __shfl_xor(ssum, 8);
                float rinv = 1.f / ssum;
                #pragma unroll
                for (int nt = 0; nt < 4; ++nt)
                    PB[(w * 16 + lg * 4 + i) * 72 + nt * 16 + lc] = f2bf(p[i][nt] * rinv);
            }
            __syncthreads();                                   // B2: P ready

            // ---- P @ V ----
            f32x4 oacc[2];
            oacc[0] = oacc[1] = fzero;
            #pragma unroll
            for (int kt = 0; kt < 2; ++kt) {
                short8 Ap = *(const short8*)(PB + (w * 16 + lc) * 72 + kt * 32 + lg * 8);
                #pragma unroll
                for (int nt2 = 0; nt2 < 2; ++nt2) {
                    short8 Bv = *(const short8*)(VT + (hh * 32 + nt2 * 16 + lc) * 72 + kt * 32 + lg * 8);
                    oacc[nt2] = __builtin_amdgcn_mfma_f32_16x16x32_bf16(Ap, Bv, oacc[nt2], 0, 0, 0);
                }
            }
            #pragma unroll
            for (int nt2 = 0; nt2 < 2; ++nt2)
                #pragma unroll
                for (int i = 0; i < 4; ++i)
                    AO[(w * 16 + lg * 4 + i) * 40 + nt2 * 16 + lc] = f2bf(oacc[nt2][i]);
            __syncthreads();                                   // B3: AO ready (also fences PB reads)

            // ---- proj accumulate: wave w owns output cols 64w.. ----
            #pragma unroll
            for (int mt = 0; mt < 4; ++mt) {
                short8 Aa = *(const short8*)(AO + (mt * 16 + lc) * 40 + lg * 8);
                #pragma unroll
                for (int ntl = 0; ntl < 4; ++ntl) {
                    short8 Bp = *(const short8*)(wps + (size_t)(((w * 4 + ntl) * 8 + h) * 64 + l) * 8);
                    accP[mt][ntl] = __builtin_amdgcn_mfma_f32_16x16x32_bf16(Aa, Bp, accP[mt][ntl], 0, 0, 0);
                }
            }
            // hh=1's PB write is fenced by B3; next g's QG/KG/VT writes are fenced by B3+B1.
        }
    }

    // ---- epilogue: out = accP + proj_b ----
    {
        float* ob = out + (size_t)blk * (LTOK * CDIM);
        float pbv[4];
        #pragma unroll
        for (int ntl = 0; ntl < 4; ++ntl) pbv[ntl] = proj_b[w * 64 + ntl * 16 + lc];
        #pragma unroll
        for (int mt = 0; mt < 4; ++mt)
            #pragma unroll
            for (int ntl = 0; ntl < 4; ++ntl)
                #pragma unroll
                for (int i = 0; i < 4; ++i)
                    ob[(mt * 16 + lg * 4 + i) * 256 + w * 64 + ntl * 16 + lc] = accP[mt][ntl][i] + pbv[ntl];
    }
}

extern "C" void kernel_launch(void* const* d_in, const int* in_sizes, int n_in,
                              void* d_out, int out_size, void* d_ws, size_t ws_size,
                              hipStream_t stream) {
    const float* x     = (const float*)d_in[0];
    const float* qkvw  = (const float*)d_in[1];
    const float* qkvb  = (const float*)d_in[2];
    const float* projw = (const float*)d_in[3];
    const float* projb = (const float*)d_in[4];
    const float* lsc   = (const float*)d_in[5];
    const float* w1    = (const float*)d_in[6];
    const float* b1    = (const float*)d_in[7];
    const float* w2    = (const float*)d_in[8];
    const float* b2    = (const float*)d_in[9];
    float* out = (float*)d_out;

    // workspace layout
    short* wqs   = (short*)d_ws;                          // 393216 B
    short* wps   = (short*)((char*)d_ws + 393216);        // 131072 B
    float* biasT = (float*)((char*)d_ws + 524288);        // 4096 B
    float* scT   = (float*)((char*)d_ws + 528384);        // 32 B

    const int nwin = in_sizes[0] / (LTOK * CDIM);         // 4096

    prep_weights<<<768, 256, 0, stream>>>(qkvw, projw, wqs, wps);
    prep_bias<<<1, 128, 0, stream>>>(w1, b1, w2, b2, lsc, biasT, scT);
    fused_win_attn<<<nwin, 256, 0, stream>>>(x, qkvb, projb, wqs, wps, biasT, scT, out);
}